// Round 8
// baseline (952.230 us; speedup 1.0000x reference)
//
#include <hip/hip_runtime.h>
#include <hip/hip_bf16.h>

using f32x4  = __attribute__((ext_vector_type(4))) float;
using bf16x8 = __attribute__((ext_vector_type(8))) __bf16;

typedef const __attribute__((address_space(1))) unsigned int GU32;
typedef __attribute__((address_space(3))) unsigned int LU32;

__device__ __forceinline__ void gload_lds16(void* l, const void* g) {
    __builtin_amdgcn_global_load_lds((GU32*)g, (LU32*)l, 16, 0, 0);
}

// ---------------------------------------------------------------------------
// Shared GEMM body (m97 structure, tile TM x TM, BK=64, 4 waves):
//   C[M,N] = A[M,K] @ W[N,K]^T (+bias)
//   global_load_lds width16 staging, LDS [kg][row][8] k-outer, conflict-free.
//   PARTIAL=1: raw fp32 partial store (c2_off = z-slice stride, zslice idx).
//   PARTIAL=0: bias + optional relu + bf16/f32 store.
//   rows >= msplit: A read at +a2_off, C stored at +c2_off (fused stacking).
// ---------------------------------------------------------------------------
template <int TM, int RELU, int BF16OUT, int PARTIAL>
__device__ __forceinline__ void gemm_body(
    bf16x8* As, bf16x8* Ws,
    const __bf16* __restrict__ A, int lda, long long a2_off, int msplit,
    const __bf16* __restrict__ Wt, int ldw, int wrows,
    const float* __restrict__ bias,
    void* __restrict__ Cout, int ldc, long long c2_off,
    int N, int K, int m0, int n0, int kb0, int ke, int zslice)
{
    constexpr int NIT = TM / 32;   // gload instrs per matrix
    constexpr int FR  = TM / 32;   // 16-wide frags per wave dim
    const int t = threadIdx.x, l = t & 63, w = t >> 6;

    const __bf16* Ab = A + ((m0 >= msplit) ? a2_off : 0);
    const __bf16* asrc[NIT];
    const __bf16* wsrc[NIT];
    int dslot[NIT];
#pragma unroll
    for (int it = 0; it < NIT; ++it) {
        int slot = (w * NIT + it) * 64 + l;
        int kg   = slot / TM;
        int row  = slot % TM;
        asrc[it] = Ab + (size_t)(m0 + row) * lda + kg * 8 + kb0;
        int wrow = n0 + row; if (wrow >= wrows) wrow = wrows - 1;
        wsrc[it] = Wt + (size_t)wrow * ldw + kg * 8 + kb0;
        dslot[it] = (w * NIT + it) * 64;
    }

    const int lr = l & 15, lkg = l >> 4;
    const int wr = (w >> 1) * (TM / 2), wc = (w & 1) * (TM / 2);

    f32x4 acc[FR][FR] = {};

    for (int kb = kb0; kb < ke; kb += 64) {
#pragma unroll
        for (int it = 0; it < NIT; ++it) {
            gload_lds16(&As[dslot[it]], asrc[it]);
            gload_lds16(&Ws[dslot[it]], wsrc[it]);
            asrc[it] += 64; wsrc[it] += 64;
        }
        __syncthreads();
#pragma unroll
        for (int ks = 0; ks < 2; ++ks) {
            const int kgf = ks * 4 + lkg;
            bf16x8 af[FR], wf[FR];
#pragma unroll
            for (int m = 0; m < FR; ++m) af[m] = As[kgf * TM + wr + m * 16 + lr];
#pragma unroll
            for (int n = 0; n < FR; ++n) wf[n] = Ws[kgf * TM + wc + n * 16 + lr];
#pragma unroll
            for (int m = 0; m < FR; ++m)
#pragma unroll
                for (int n = 0; n < FR; ++n)
                    acc[m][n] = __builtin_amdgcn_mfma_f32_16x16x32_bf16(
                        af[m], wf[n], acc[m][n], 0, 0, 0);
        }
        __syncthreads();
    }

    // epilogue: C/D layout col = lane&15, row = (lane>>4)*4 + j (m89-verified)
    const long long coff = PARTIAL ? (long long)zslice * c2_off
                                   : ((m0 >= msplit) ? c2_off : 0);
#pragma unroll
    for (int n = 0; n < FR; ++n) {
        int col = n0 + wc + n * 16 + lr;
        if (col >= N) continue;
        float bv = PARTIAL ? 0.f : bias[col];
#pragma unroll
        for (int m = 0; m < FR; ++m) {
            int rbase = m0 + wr + m * 16 + lkg * 4;
#pragma unroll
            for (int j = 0; j < 4; ++j) {
                long long idx = (long long)(rbase + j) * ldc + col + coff;
                if (PARTIAL) {
                    ((float*)Cout)[idx] = acc[m][n][j];
                } else {
                    float v = acc[m][n][j] + bv;
                    if (RELU) v = fmaxf(v, 0.f);
                    if (BF16OUT) ((__bf16*)Cout)[idx] = (__bf16)v;
                    else         ((float*)Cout)[idx]  = v;
                }
            }
        }
    }
}

// 128x128 tile wrapper (big GEMMs, optional split-K via blockIdx.z)
template <int RELU, int BF16OUT, int PARTIAL>
__global__ __launch_bounds__(256)
void gemm128(const __bf16* __restrict__ A, int lda, long long a2_off, int msplit,
             const __bf16* __restrict__ Wt, int ldw, int wrows,
             const float* __restrict__ bias,
             void* __restrict__ Cout, int ldc, long long c2_off,
             int N, int K, int kchunk)
{
    __shared__ bf16x8 As[1024];
    __shared__ bf16x8 Ws[1024];
    int kb0 = blockIdx.z * kchunk;
    int ke  = min(kb0 + kchunk, K);
    gemm_body<128, RELU, BF16OUT, PARTIAL>(
        As, Ws, A, lda, a2_off, msplit, Wt, ldw, wrows, bias,
        Cout, ldc, c2_off, N, K, blockIdx.y << 7, blockIdx.x << 7,
        kb0, ke, blockIdx.z);
}

// 64x64 tile, full-K, direct epilogue; two descriptor sets in one launch
struct GDesc {
    const __bf16* A; const __bf16* W; const float* bias; void* out;
    long long a2, c2;
    int lda, ldw, wrows, ldc, N, K, ntx, msplit;
};

template <int RELU, int BF16OUT>
__global__ __launch_bounds__(256)
void gemm64_dual(GDesc d0, GDesc d1, int nblk0)
{
    __shared__ bf16x8 As[512];
    __shared__ bf16x8 Ws[512];
    int bid = blockIdx.x;
    GDesc d = (bid < nblk0) ? d0 : d1;
    int tid = (bid < nblk0) ? bid : bid - nblk0;
    int tx = tid % d.ntx, ty = tid / d.ntx;
    gemm_body<64, RELU, BF16OUT, 0>(
        As, Ws, d.A, d.lda, d.a2, d.msplit, d.W, d.ldw, d.wrows, d.bias,
        d.out, d.ldc, d.c2, d.N, d.K, ty << 6, tx << 6, 0, d.K, 0);
}

// out = act(sum_s part[s] + bias); row>=msplit stores at +c2
template <int RELU, int BF16OUT>
__global__ __launch_bounds__(256)
void reduce_k(const float* __restrict__ part, long long zs, int S,
              const float* __restrict__ bias, void* __restrict__ out,
              int N, int ldc, int msplit, long long c2, int M)
{
    const int n8 = N >> 3;
    const long long total = (long long)M * n8;
    for (long long i = (long long)blockIdx.x * 256 + threadIdx.x; i < total;
         i += (long long)gridDim.x * 256) {
        int row = (int)(i / n8);
        int c8  = (int)(i - (long long)row * n8) << 3;
        long long base = (long long)row * N + c8;
        float4 s0 = {0.f, 0.f, 0.f, 0.f}, s1 = {0.f, 0.f, 0.f, 0.f};
        for (int s = 0; s < S; ++s) {
            const float4* p = (const float4*)(part + s * zs + base);
            float4 a = p[0], b = p[1];
            s0.x += a.x; s0.y += a.y; s0.z += a.z; s0.w += a.w;
            s1.x += b.x; s1.y += b.y; s1.z += b.z; s1.w += b.w;
        }
        float v[8] = {s0.x, s0.y, s0.z, s0.w, s1.x, s1.y, s1.z, s1.w};
        long long ob = (long long)row * ldc + c8 + ((row >= msplit) ? c2 : 0);
        if (BF16OUT) {
            bf16x8 o;
#pragma unroll
            for (int j = 0; j < 8; ++j) {
                float x = v[j] + bias[c8 + j];
                if (RELU) x = fmaxf(x, 0.f);
                o[j] = (__bf16)x;
            }
            *(bf16x8*)((__bf16*)out + ob) = o;
        } else {
            float t0[8];
#pragma unroll
            for (int j = 0; j < 8; ++j) {
                float x = v[j] + bias[c8 + j];
                if (RELU) x = fmaxf(x, 0.f);
                t0[j] = x;
            }
            float4 o0 = {t0[0], t0[1], t0[2], t0[3]};
            float4 o1 = {t0[4], t0[5], t0[6], t0[7]};
            *(float4*)((float*)out + ob)     = o0;
            *(float4*)((float*)out + ob + 4) = o1;
        }
    }
}

// fp32 -> bf16 (optional relu), n multiple of 8
__global__ __launch_bounds__(256)
void conv_bf16(const float* __restrict__ in, __bf16* __restrict__ out,
               long long n, int relu)
{
    long long stride = (long long)gridDim.x * 256 * 8;
    for (long long i = ((long long)blockIdx.x * 256 + threadIdx.x) * 8; i < n; i += stride) {
        float4 f0 = *(const float4*)(in + i);
        float4 f1 = *(const float4*)(in + i + 4);
        float v[8] = {f0.x, f0.y, f0.z, f0.w, f1.x, f1.y, f1.z, f1.w};
        bf16x8 o;
#pragma unroll
        for (int j = 0; j < 8; ++j) {
            float x = v[j];
            if (relu) x = fmaxf(x, 0.f);
            o[j] = (__bf16)x;
        }
        *(bf16x8*)(out + i) = o;
    }
}

// fp32 [rows][cols] -> bf16 [rows][ldo], zero-padded cols..ldo-1
__global__ __launch_bounds__(256)
void conv_pad(const float* __restrict__ in, __bf16* __restrict__ out,
              int rows, int cols, int ldo)
{
    int v8 = ldo >> 3;
    long long total = (long long)rows * v8;
    for (long long s = (long long)blockIdx.x * 256 + threadIdx.x; s < total;
         s += (long long)gridDim.x * 256) {
        int r  = (int)(s / v8);
        int c8 = ((int)(s % v8)) << 3;
        bf16x8 o;
        if (c8 + 8 <= cols) {
            const float* p = in + (size_t)r * cols + c8;
            float4 f0 = *(const float4*)p;
            float4 f1 = *(const float4*)(p + 4);
            float v[8] = {f0.x, f0.y, f0.z, f0.w, f1.x, f1.y, f1.z, f1.w};
#pragma unroll
            for (int j = 0; j < 8; ++j) o[j] = (__bf16)v[j];
        } else {
#pragma unroll
            for (int j = 0; j < 8; ++j) o[j] = (__bf16)0.f;
        }
        *(bf16x8*)(out + (size_t)r * ldo + c8) = o;
    }
}

__global__ __launch_bounds__(256)
void zero_cols(__bf16* __restrict__ buf, int rows, int c0, int ld)
{
    int wpad = ld - c0;
    int total = rows * wpad;
    for (int i = blockIdx.x * 256 + threadIdx.x; i < total; i += gridDim.x * 256)
        buf[(size_t)(i / wpad) * ld + c0 + (i % wpad)] = (__bf16)0.f;
}

__global__ __launch_bounds__(256)
void score_kernel(const float* __restrict__ emb,
                  const float* __restrict__ labels,
                  const int* __restrict__ pls,
                  const int* __restrict__ nls,
                  float* __restrict__ out)
{
    const int b = blockIdx.x;
    __shared__ float e[600];
    for (int i = threadIdx.x; i < 600; i += 256) e[i] = emb[(size_t)b * 600 + i];
    __syncthreads();

    const int w = threadIdx.x >> 6;
    const int lane = threadIdx.x & 63;
    for (int j = w; j < 129; j += 4) {
        int idx = (j == 0) ? pls[b] : nls[(size_t)b * 128 + (j - 1)];
        const float* lv = labels + (size_t)idx * 600;
        float s = 0.f;
        for (int d = lane; d < 600; d += 64) {
            float df = lv[d] - e[d];
            df = fmaxf(df, 0.f);
            s += df * df;
        }
#pragma unroll
        for (int off = 32; off >= 1; off >>= 1) s += __shfl_xor(s, off, 64);
        if (lane == 0) out[(size_t)b * 129 + j] = -sqrtf(s);
    }
}

extern "C" void kernel_launch(void* const* d_in, const int* in_sizes, int n_in,
                              void* d_out, int out_size, void* d_ws, size_t ws_size,
                              hipStream_t stream)
{
    const float* vfs    = (const float*)d_in[0];
    const float* labels = (const float*)d_in[1];
    const int*   pls    = (const int*)d_in[2];
    const int*   nls    = (const int*)d_in[3];
    const float* W_h1   = (const float*)d_in[4];
    const float* b_h1   = (const float*)d_in[5];
    const float* W_e1   = (const float*)d_in[6];
    const float* b_e1   = (const float*)d_in[7];
    const float* W_h2   = (const float*)d_in[8];
    const float* b_h2   = (const float*)d_in[9];
    const float* W_e2   = (const float*)d_in[10];
    const float* b_e2   = (const float*)d_in[11];
    const float* W_h    = (const float*)d_in[12];
    const float* b_h    = (const float*)d_in[13];
    const float* W_e    = (const float*)d_in[14];
    const float* b_e    = (const float*)d_in[15];

    char* p = (char*)d_ws;
    auto alloc = [&](size_t bytes) { char* r = p; p += (bytes + 255) & ~size_t(255); return r; };
    __bf16* vfs_bf = (__bf16*)alloc(1024ll * 12288 * 2);
    __bf16* h1     = (__bf16*)alloc(2048ll * 2048 * 2);
    __bf16* hp     = (__bf16*)alloc(1024ll * 4096 * 2);
    __bf16* z      = (__bf16*)alloc(1024ll * 1856 * 2);
    __bf16* h2     = (__bf16*)alloc(1024ll * 1856 * 2);
    float*  emb    = (float*)alloc(1024ll * 600 * 4);
    __bf16* Wh1b   = (__bf16*)alloc(2048ll * 4096 * 2);
    __bf16* Wh2b   = (__bf16*)alloc(4096ll * 12288 * 2);
    __bf16* We1b   = (__bf16*)alloc(600ll * 2048 * 2);
    __bf16* We2b   = (__bf16*)alloc(600ll * 4096 * 2);
    __bf16* Whb    = (__bf16*)alloc(1800ll * 1856 * 2);
    __bf16* Web    = (__bf16*)alloc(600ll * 1856 * 2);

    // split-K partial arena for the two big GEMMs, capped at 64 MB
    size_t used  = (size_t)(p - (char*)d_ws);
    size_t rem   = (ws_size > used) ? (ws_size - used) : 0;
    size_t arena = rem > (64u << 20) ? (64u << 20) : (rem & ~size_t(255));
    float* part  = (float*)alloc(arena);

    dim3 blk(256);
    const int HUGE_SPLIT = 1 << 30;

    auto pickS = [&](int M, int N, int smax) {
        int s = smax;
        while (s > 1 && (long long)s * M * N * 4 > (long long)arena) s >>= 1;
        return s;
    };
    // big-GEMM launcher (128^2): S>1 -> partial+reduce, S==1 -> direct
    auto gemm = [&](const __bf16* A, int lda, long long a2, int msA,
                    const __bf16* W, int ldw, int wrows, const float* bias,
                    void* out, int ldc, int msC, long long c2,
                    int M, int N, int K, int smax) {
        int S = pickS(M, N, smax);
        int nx = (N + 127) >> 7, ny = M >> 7;
        if (S == 1) {
            gemm128<1, 1, 0><<<dim3(nx, ny, 1), blk, 0, stream>>>(
                A, lda, a2, (msA == HUGE_SPLIT ? msC : msA), W, ldw, wrows,
                bias, out, ldc, c2, N, K, K);
        } else {
            int kchunk = (((K + S - 1) / S) + 63) & ~63;
            long long zs = (long long)M * N;
            gemm128<0, 0, 1><<<dim3(nx, ny, S), blk, 0, stream>>>(
                A, lda, a2, msA, W, ldw, wrows, nullptr,
                part, N, zs, N, K, kchunk);
            long long tot8 = (long long)M * (N >> 3);
            int rblocks = (int)((tot8 + 255) / 256);
            if (rblocks > 2048) rblocks = 2048;
            reduce_k<1, 1><<<dim3(rblocks), blk, 0, stream>>>(
                part, zs, S, bias, out, N, ldc, msC, c2, M);
        }
    };

    // ---- conversions --------------------------------------------------
    conv_bf16<<<2048, blk, 0, stream>>>(vfs, vfs_bf, 1024ll * 12288, 1);
    conv_bf16<<<1024, blk, 0, stream>>>(W_h1, Wh1b, 2048ll * 4096, 0);
    conv_bf16<<<2048, blk, 0, stream>>>(W_h2, Wh2b, 4096ll * 12288, 0);
    conv_bf16<<<512,  blk, 0, stream>>>(W_e1, We1b, 600ll * 2048, 0);
    conv_bf16<<<512,  blk, 0, stream>>>(W_e2, We2b, 600ll * 4096, 0);
    conv_pad<<<1024, blk, 0, stream>>>(W_h, Whb, 1800, 1800, 1856);
    conv_pad<<<512,  blk, 0, stream>>>(W_e, Web, 600, 1800, 1856);
    zero_cols<<<256, blk, 0, stream>>>(z,  1024, 1800, 1856);
    zero_cols<<<256, blk, 0, stream>>>(h2, 1024, 1800, 1856);

    // ---- big GEMMs (128^2 split-K) ------------------------------------
    // 1) layer-1 hidden, sbj+obj fused: M=2048, K=4096, S=4 -> 1024 blocks
    gemm(vfs_bf, 12288, 8192ll - 1024ll * 12288, 1024,
         Wh1b, 4096, 2048, b_h1, h1, 2048, HUGE_SPLIT, 0,
         2048, 2048, 4096, 4);
    // 2) layer-1 hidden, pre: M=1024, N=4096, K=12288, S=4 -> 1024 blocks
    gemm(vfs_bf, 12288, 0, HUGE_SPLIT,
         Wh2b, 12288, 4096, b_h2, hp, 4096, HUGE_SPLIT, 0,
         1024, 4096, 12288, 4);

    // ---- tail GEMMs (64^2 full-K, direct epilogue) --------------------
    // 3+4) e-layers merged: G3 (h1 -> z[:,0:600]+[1200:1800]) 320 blocks,
    //                       G4 (hp -> z[:,600:1200]) 160 blocks
    {
        GDesc d3{h1,  We1b, b_e1, z,       0, 1200ll - 1024ll * 1856,
                 2048, 2048, 600, 1856, 600, 2048, 10, 1024};
        GDesc d4{hp,  We2b, b_e2, z + 600, 0, 0,
                 4096, 4096, 600, 1856, 600, 4096, 10, HUGE_SPLIT};
        gemm64_dual<1, 1><<<dim3(480), blk, 0, stream>>>(d3, d4, 320);
    }
    // 5) fusion hidden: h2 = relu(z @ W_h^T + b_h), 29x16 = 464 blocks
    {
        GDesc d5{z, Whb, b_h, h2, 0, 0,
                 1856, 1856, 1800, 1856, 1800, 1856, 29, HUGE_SPLIT};
        gemm64_dual<1, 1><<<dim3(464), blk, 0, stream>>>(d5, d5, 464);
    }
    // 6) embedding: emb = h2 @ W_e^T + b_e (fp32 out, no relu), 160 blocks
    {
        GDesc d6{h2, Web, b_e, emb, 0, 0,
                 1856, 1856, 600, 600, 600, 1856, 10, HUGE_SPLIT};
        gemm64_dual<0, 0><<<dim3(160), blk, 0, stream>>>(d6, d6, 160);
    }

    // ---- scores -------------------------------------------------------
    score_kernel<<<dim3(1024), blk, 0, stream>>>(emb, labels, pls, nls, (float*)d_out);
}

// Round 13
// 877.005 us; speedup vs baseline: 1.0858x; 1.0858x over previous
//
#include <hip/hip_runtime.h>
#include <hip/hip_bf16.h>

using f32x4  = __attribute__((ext_vector_type(4))) float;
using bf16x8 = __attribute__((ext_vector_type(8))) __bf16;

typedef const __attribute__((address_space(1))) unsigned int GU32;
typedef __attribute__((address_space(3))) unsigned int LU32;

__device__ __forceinline__ void gload_lds16(void* l, const void* g) {
    // async global->LDS, 16B/lane; LDS dst = wave-uniform base + lane*16
    __builtin_amdgcn_global_load_lds((GU32*)g, (LU32*)l, 16, 0, 0);
}

// ---------------------------------------------------------------------------
// 256x256-tile, BK=64, 8-wave (2Mx4N) double-buffered GEMM with counted
// vmcnt pipeline (T3/T4): C[M,N] = A[M,K] @ W[N,K]^T.
//   - LDS: 2 x (A 32KB + B 32KB) = 128 KB; 1 block/CU; per-wave out 128x64.
//   - iter tt: wait vmcnt(8) [tile tt landed, tt+1 in flight] -> s_barrier ->
//     compute buf[tt&1] -> lgkmcnt(0) -> s_barrier -> stage tt+2 into buf[tt&1]
//   - raw s_barrier (NOT __syncthreads: that drains vmcnt(0)).
//   - M, N multiples of 256 (enforced by caller).
//   - PARTIAL=1: fp32 partial store (split-K), c2_off = slice stride.
// ---------------------------------------------------------------------------
template <int RELU, int BF16OUT, int PARTIAL>
__global__ __launch_bounds__(512)
void gemm256_2ph(const __bf16* __restrict__ A, int lda, long long a2_off, int msplit,
                 const __bf16* __restrict__ Wt, int ldw, int wrows,
                 const float* __restrict__ bias,
                 void* __restrict__ Cout, int ldc, long long c2_off,
                 int N, int K, int kchunk)
{
    __shared__ bf16x8 As[2][2048];   // [kg(8)][row(256)] per buffer, 32 KB
    __shared__ bf16x8 Ws[2][2048];

    const int t = threadIdx.x, l = t & 63, w = t >> 6;
    const int m0 = blockIdx.y << 8;
    const int n0 = blockIdx.x << 8;
    const int kb0 = blockIdx.z * kchunk;
    const int NT  = (min(kb0 + kchunk, K) - kb0) >> 6;

    const __bf16* Ab = A + ((m0 >= msplit) ? a2_off : 0);

    // staging: 4 instrs per matrix; slot = it*512 + t; kg = slot>>8, row = slot&255
    const __bf16* asrc[4];
    const __bf16* wsrc[4];
    int dbase[4];
#pragma unroll
    for (int it = 0; it < 4; ++it) {
        int slot = it * 512 + t;
        int kg = slot >> 8, row = slot & 255;
        asrc[it] = Ab + (size_t)(m0 + row) * lda + kg * 8 + kb0;
        int wrow = n0 + row; if (wrow >= wrows) wrow = wrows - 1;
        wsrc[it] = Wt + (size_t)wrow * ldw + kg * 8 + kb0;
        dbase[it] = it * 512 + w * 64;   // wave-uniform LDS base slot
    }

    auto stage = [&](int buf, int koff) {
#pragma unroll
        for (int it = 0; it < 4; ++it)
            gload_lds16(&As[buf][dbase[it]], asrc[it] + koff);
#pragma unroll
        for (int it = 0; it < 4; ++it)
            gload_lds16(&Ws[buf][dbase[it]], wsrc[it] + koff);
    };

    const int lr = l & 15, lkg = l >> 4;
    const int wr = (w >> 2) << 7;    // wave row offset (0/128)
    const int wc = (w & 3) << 6;     // wave col offset (0..192)

    f32x4 acc[8][4] = {};

    stage(0, 0);
    if (NT > 1) stage(1, 64);

    for (int tt = 0; tt < NT; ++tt) {
        if (tt + 1 < NT) asm volatile("s_waitcnt vmcnt(8)" ::: "memory");
        else             asm volatile("s_waitcnt vmcnt(0)" ::: "memory");
        __builtin_amdgcn_sched_barrier(0);
        __builtin_amdgcn_s_barrier();
        __builtin_amdgcn_sched_barrier(0);

        const bf16x8* Al = As[tt & 1];
        const bf16x8* Wl = Ws[tt & 1];
#pragma unroll
        for (int ks = 0; ks < 2; ++ks) {
            const int kgf = ks * 4 + lkg;
            bf16x8 af[8], wf[4];
#pragma unroll
            for (int m = 0; m < 8; ++m) af[m] = Al[kgf * 256 + wr + m * 16 + lr];
#pragma unroll
            for (int n = 0; n < 4; ++n) wf[n] = Wl[kgf * 256 + wc + n * 16 + lr];
#pragma unroll
            for (int m = 0; m < 8; ++m)
#pragma unroll
                for (int n = 0; n < 4; ++n)
                    acc[m][n] = __builtin_amdgcn_mfma_f32_16x16x32_bf16(
                        af[m], wf[n], acc[m][n], 0, 0, 0);
        }

        asm volatile("s_waitcnt lgkmcnt(0)" ::: "memory");
        __builtin_amdgcn_sched_barrier(0);
        __builtin_amdgcn_s_barrier();
        __builtin_amdgcn_sched_barrier(0);
        if (tt + 2 < NT) stage(tt & 1, (tt + 2) << 6);
    }

    // epilogue: C/D layout col = lane&15, row = (lane>>4)*4 + j (m89-verified)
    const long long coff = PARTIAL ? (long long)blockIdx.z * c2_off
                                   : ((m0 >= msplit) ? c2_off : 0);
#pragma unroll
    for (int n = 0; n < 4; ++n) {
        int col = n0 + wc + n * 16 + lr;
        if (col >= N) continue;
        float bv = PARTIAL ? 0.f : bias[col];
#pragma unroll
        for (int m = 0; m < 8; ++m) {
            int rbase = m0 + wr + m * 16 + lkg * 4;
#pragma unroll
            for (int j = 0; j < 4; ++j) {
                long long idx = (long long)(rbase + j) * ldc + col + coff;
                if (PARTIAL) {
                    ((float*)Cout)[idx] = acc[m][n][j];
                } else {
                    float v = acc[m][n][j] + bv;
                    if (RELU) v = fmaxf(v, 0.f);
                    if (BF16OUT) ((__bf16*)Cout)[idx] = (__bf16)v;
                    else         ((float*)Cout)[idx]  = v;
                }
            }
        }
    }
}

// ---------------------------------------------------------------------------
// Shared GEMM body (m97 structure, tile TM x TM, BK=64, 4 waves) — verified.
// ---------------------------------------------------------------------------
template <int TM, int RELU, int BF16OUT, int PARTIAL>
__device__ __forceinline__ void gemm_body(
    bf16x8* As, bf16x8* Ws,
    const __bf16* __restrict__ A, int lda, long long a2_off, int msplit,
    const __bf16* __restrict__ Wt, int ldw, int wrows,
    const float* __restrict__ bias,
    void* __restrict__ Cout, int ldc, long long c2_off,
    int N, int K, int m0, int n0, int kb0, int ke, int zslice)
{
    constexpr int NIT = TM / 32;
    constexpr int FR  = TM / 32;
    const int t = threadIdx.x, l = t & 63, w = t >> 6;

    const __bf16* Ab = A + ((m0 >= msplit) ? a2_off : 0);
    const __bf16* asrc[NIT];
    const __bf16* wsrc[NIT];
    int dslot[NIT];
#pragma unroll
    for (int it = 0; it < NIT; ++it) {
        int slot = (w * NIT + it) * 64 + l;
        int kg   = slot / TM;
        int row  = slot % TM;
        asrc[it] = Ab + (size_t)(m0 + row) * lda + kg * 8 + kb0;
        int wrow = n0 + row; if (wrow >= wrows) wrow = wrows - 1;
        wsrc[it] = Wt + (size_t)wrow * ldw + kg * 8 + kb0;
        dslot[it] = (w * NIT + it) * 64;
    }

    const int lr = l & 15, lkg = l >> 4;
    const int wr = (w >> 1) * (TM / 2), wc = (w & 1) * (TM / 2);

    f32x4 acc[FR][FR] = {};

    for (int kb = kb0; kb < ke; kb += 64) {
#pragma unroll
        for (int it = 0; it < NIT; ++it) {
            gload_lds16(&As[dslot[it]], asrc[it]);
            gload_lds16(&Ws[dslot[it]], wsrc[it]);
            asrc[it] += 64; wsrc[it] += 64;
        }
        __syncthreads();
#pragma unroll
        for (int ks = 0; ks < 2; ++ks) {
            const int kgf = ks * 4 + lkg;
            bf16x8 af[FR], wf[FR];
#pragma unroll
            for (int m = 0; m < FR; ++m) af[m] = As[kgf * TM + wr + m * 16 + lr];
#pragma unroll
            for (int n = 0; n < FR; ++n) wf[n] = Ws[kgf * TM + wc + n * 16 + lr];
#pragma unroll
            for (int m = 0; m < FR; ++m)
#pragma unroll
                for (int n = 0; n < FR; ++n)
                    acc[m][n] = __builtin_amdgcn_mfma_f32_16x16x32_bf16(
                        af[m], wf[n], acc[m][n], 0, 0, 0);
        }
        __syncthreads();
    }

    const long long coff = PARTIAL ? (long long)zslice * c2_off
                                   : ((m0 >= msplit) ? c2_off : 0);
#pragma unroll
    for (int n = 0; n < FR; ++n) {
        int col = n0 + wc + n * 16 + lr;
        if (col >= N) continue;
        float bv = PARTIAL ? 0.f : bias[col];
#pragma unroll
        for (int m = 0; m < FR; ++m) {
            int rbase = m0 + wr + m * 16 + lkg * 4;
#pragma unroll
            for (int j = 0; j < 4; ++j) {
                long long idx = (long long)(rbase + j) * ldc + col + coff;
                if (PARTIAL) {
                    ((float*)Cout)[idx] = acc[m][n][j];
                } else {
                    float v = acc[m][n][j] + bv;
                    if (RELU) v = fmaxf(v, 0.f);
                    if (BF16OUT) ((__bf16*)Cout)[idx] = (__bf16)v;
                    else         ((float*)Cout)[idx]  = v;
                }
            }
        }
    }
}

template <int RELU, int BF16OUT, int PARTIAL>
__global__ __launch_bounds__(256)
void gemm128(const __bf16* __restrict__ A, int lda, long long a2_off, int msplit,
             const __bf16* __restrict__ Wt, int ldw, int wrows,
             const float* __restrict__ bias,
             void* __restrict__ Cout, int ldc, long long c2_off,
             int N, int K, int kchunk)
{
    __shared__ bf16x8 As[1024];
    __shared__ bf16x8 Ws[1024];
    int kb0 = blockIdx.z * kchunk;
    int ke  = min(kb0 + kchunk, K);
    gemm_body<128, RELU, BF16OUT, PARTIAL>(
        As, Ws, A, lda, a2_off, msplit, Wt, ldw, wrows, bias,
        Cout, ldc, c2_off, N, K, blockIdx.y << 7, blockIdx.x << 7,
        kb0, ke, blockIdx.z);
}

struct GDesc {
    const __bf16* A; const __bf16* W; const float* bias; void* out;
    long long a2, c2;
    int lda, ldw, wrows, ldc, N, K, ntx, msplit;
};

template <int RELU, int BF16OUT>
__global__ __launch_bounds__(256)
void gemm64_dual(GDesc d0, GDesc d1, int nblk0)
{
    __shared__ bf16x8 As[512];
    __shared__ bf16x8 Ws[512];
    int bid = blockIdx.x;
    GDesc d = (bid < nblk0) ? d0 : d1;
    int tid = (bid < nblk0) ? bid : bid - nblk0;
    int tx = tid % d.ntx, ty = tid / d.ntx;
    gemm_body<64, RELU, BF16OUT, 0>(
        As, Ws, d.A, d.lda, d.a2, d.msplit, d.W, d.ldw, d.wrows, d.bias,
        d.out, d.ldc, d.c2, d.N, d.K, ty << 6, tx << 6, 0, d.K, 0);
}

template <int RELU, int BF16OUT>
__global__ __launch_bounds__(256)
void reduce_k(const float* __restrict__ part, long long zs, int S,
              const float* __restrict__ bias, void* __restrict__ out,
              int N, int ldc, int msplit, long long c2, int M)
{
    const int n8 = N >> 3;
    const long long total = (long long)M * n8;
    for (long long i = (long long)blockIdx.x * 256 + threadIdx.x; i < total;
         i += (long long)gridDim.x * 256) {
        int row = (int)(i / n8);
        int c8  = (int)(i - (long long)row * n8) << 3;
        long long base = (long long)row * N + c8;
        float4 s0 = {0.f, 0.f, 0.f, 0.f}, s1 = {0.f, 0.f, 0.f, 0.f};
        for (int s = 0; s < S; ++s) {
            const float4* p = (const float4*)(part + s * zs + base);
            float4 a = p[0], b = p[1];
            s0.x += a.x; s0.y += a.y; s0.z += a.z; s0.w += a.w;
            s1.x += b.x; s1.y += b.y; s1.z += b.z; s1.w += b.w;
        }
        float v[8] = {s0.x, s0.y, s0.z, s0.w, s1.x, s1.y, s1.z, s1.w};
        long long ob = (long long)row * ldc + c8 + ((row >= msplit) ? c2 : 0);
        if (BF16OUT) {
            bf16x8 o;
#pragma unroll
            for (int j = 0; j < 8; ++j) {
                float x = v[j] + bias[c8 + j];
                if (RELU) x = fmaxf(x, 0.f);
                o[j] = (__bf16)x;
            }
            *(bf16x8*)((__bf16*)out + ob) = o;
        } else {
            float t0[8];
#pragma unroll
            for (int j = 0; j < 8; ++j) {
                float x = v[j] + bias[c8 + j];
                if (RELU) x = fmaxf(x, 0.f);
                t0[j] = x;
            }
            float4 o0 = {t0[0], t0[1], t0[2], t0[3]};
            float4 o1 = {t0[4], t0[5], t0[6], t0[7]};
            *(float4*)((float*)out + ob)     = o0;
            *(float4*)((float*)out + ob + 4) = o1;
        }
    }
}

__global__ __launch_bounds__(256)
void conv_bf16(const float* __restrict__ in, __bf16* __restrict__ out,
               long long n, int relu)
{
    long long stride = (long long)gridDim.x * 256 * 8;
    for (long long i = ((long long)blockIdx.x * 256 + threadIdx.x) * 8; i < n; i += stride) {
        float4 f0 = *(const float4*)(in + i);
        float4 f1 = *(const float4*)(in + i + 4);
        float v[8] = {f0.x, f0.y, f0.z, f0.w, f1.x, f1.y, f1.z, f1.w};
        bf16x8 o;
#pragma unroll
        for (int j = 0; j < 8; ++j) {
            float x = v[j];
            if (relu) x = fmaxf(x, 0.f);
            o[j] = (__bf16)x;
        }
        *(bf16x8*)(out + i) = o;
    }
}

__global__ __launch_bounds__(256)
void conv_pad(const float* __restrict__ in, __bf16* __restrict__ out,
              int rows, int cols, int ldo)
{
    int v8 = ldo >> 3;
    long long total = (long long)rows * v8;
    for (long long s = (long long)blockIdx.x * 256 + threadIdx.x; s < total;
         s += (long long)gridDim.x * 256) {
        int r  = (int)(s / v8);
        int c8 = ((int)(s % v8)) << 3;
        bf16x8 o;
        if (c8 + 8 <= cols) {
            const float* p = in + (size_t)r * cols + c8;
            float4 f0 = *(const float4*)p;
            float4 f1 = *(const float4*)(p + 4);
            float v[8] = {f0.x, f0.y, f0.z, f0.w, f1.x, f1.y, f1.z, f1.w};
#pragma unroll
            for (int j = 0; j < 8; ++j) o[j] = (__bf16)v[j];
        } else {
#pragma unroll
            for (int j = 0; j < 8; ++j) o[j] = (__bf16)0.f;
        }
        *(bf16x8*)(out + (size_t)r * ldo + c8) = o;
    }
}

__global__ __launch_bounds__(256)
void zero_cols(__bf16* __restrict__ buf, int rows, int c0, int ld)
{
    int wpad = ld - c0;
    int total = rows * wpad;
    for (int i = blockIdx.x * 256 + threadIdx.x; i < total; i += gridDim.x * 256)
        buf[(size_t)(i / wpad) * ld + c0 + (i % wpad)] = (__bf16)0.f;
}

__global__ __launch_bounds__(256)
void score_kernel(const float* __restrict__ emb,
                  const float* __restrict__ labels,
                  const int* __restrict__ pls,
                  const int* __restrict__ nls,
                  float* __restrict__ out)
{
    const int b = blockIdx.x;
    __shared__ float e[600];
    for (int i = threadIdx.x; i < 600; i += 256) e[i] = emb[(size_t)b * 600 + i];
    __syncthreads();

    const int w = threadIdx.x >> 6;
    const int lane = threadIdx.x & 63;
    for (int j = w; j < 129; j += 4) {
        int idx = (j == 0) ? pls[b] : nls[(size_t)b * 128 + (j - 1)];
        const float* lv = labels + (size_t)idx * 600;
        float s = 0.f;
        for (int d = lane; d < 600; d += 64) {
            float df = lv[d] - e[d];
            df = fmaxf(df, 0.f);
            s += df * df;
        }
#pragma unroll
        for (int off = 32; off >= 1; off >>= 1) s += __shfl_xor(s, off, 64);
        if (lane == 0) out[(size_t)b * 129 + j] = -sqrtf(s);
    }
}

extern "C" void kernel_launch(void* const* d_in, const int* in_sizes, int n_in,
                              void* d_out, int out_size, void* d_ws, size_t ws_size,
                              hipStream_t stream)
{
    const float* vfs    = (const float*)d_in[0];
    const float* labels = (const float*)d_in[1];
    const int*   pls    = (const int*)d_in[2];
    const int*   nls    = (const int*)d_in[3];
    const float* W_h1   = (const float*)d_in[4];
    const float* b_h1   = (const float*)d_in[5];
    const float* W_e1   = (const float*)d_in[6];
    const float* b_e1   = (const float*)d_in[7];
    const float* W_h2   = (const float*)d_in[8];
    const float* b_h2   = (const float*)d_in[9];
    const float* W_e2   = (const float*)d_in[10];
    const float* b_e2   = (const float*)d_in[11];
    const float* W_h    = (const float*)d_in[12];
    const float* b_h    = (const float*)d_in[13];
    const float* W_e    = (const float*)d_in[14];
    const float* b_e    = (const float*)d_in[15];

    char* p = (char*)d_ws;
    auto alloc = [&](size_t bytes) { char* r = p; p += (bytes + 255) & ~size_t(255); return r; };
    __bf16* vfs_bf = (__bf16*)alloc(1024ll * 12288 * 2);
    __bf16* h1     = (__bf16*)alloc(2048ll * 2048 * 2);
    __bf16* hp     = (__bf16*)alloc(1024ll * 4096 * 2);
    __bf16* z      = (__bf16*)alloc(1024ll * 1856 * 2);
    __bf16* h2     = (__bf16*)alloc(1024ll * 1856 * 2);
    float*  emb    = (float*)alloc(1024ll * 600 * 4);
    __bf16* Wh1b   = (__bf16*)alloc(2048ll * 4096 * 2);
    __bf16* Wh2b   = (__bf16*)alloc(4096ll * 12288 * 2);
    __bf16* We1b   = (__bf16*)alloc(600ll * 2048 * 2);
    __bf16* We2b   = (__bf16*)alloc(600ll * 4096 * 2);
    __bf16* Whb    = (__bf16*)alloc(1800ll * 1856 * 2);
    __bf16* Web    = (__bf16*)alloc(600ll * 1856 * 2);

    size_t used  = (size_t)(p - (char*)d_ws);
    size_t rem   = (ws_size > used) ? (ws_size - used) : 0;
    size_t arena = rem > (64u << 20) ? (64u << 20) : (rem & ~size_t(255));
    float* part  = (float*)alloc(arena);

    dim3 blk(256);
    const int HUGE_SPLIT = 1 << 30;

    auto pickS = [&](int M, int N, int smax) {
        int s = smax;
        while (s > 1 && (long long)s * M * N * 4 > (long long)arena) s >>= 1;
        return s;
    };
    // big-GEMM launcher: 256^2 2-phase pipelined when S>=2 (M,N %256==0),
    // else verified 128^2 direct.
    auto gemmBig = [&](const __bf16* A, int lda, long long a2, int msA,
                       const __bf16* W, int ldw, int wrows, const float* bias,
                       void* out, int ldc, int msC, long long c2,
                       int M, int N, int K, int smax) {
        int S = pickS(M, N, smax);
        if (S >= 2 && (M % 256) == 0 && (N % 256) == 0) {
            int kchunk = (((K + S - 1) / S) + 63) & ~63;
            long long zs = (long long)M * N;
            gemm256_2ph<0, 0, 1><<<dim3(N >> 8, M >> 8, S), dim3(512), 0, stream>>>(
                A, lda, a2, msA, W, ldw, wrows, nullptr,
                part, N, zs, N, K, kchunk);
            long long tot8 = (long long)M * (N >> 3);
            int rblocks = (int)((tot8 + 255) / 256);
            if (rblocks > 2048) rblocks = 2048;
            reduce_k<1, 1><<<dim3(rblocks), blk, 0, stream>>>(
                part, zs, S, bias, out, N, ldc, msC, c2, M);
        } else {
            gemm128<1, 1, 0><<<dim3((N + 127) >> 7, M >> 7, 1), blk, 0, stream>>>(
                A, lda, a2, (msA == HUGE_SPLIT ? msC : msA), W, ldw, wrows,
                bias, out, ldc, c2, N, K, K);
        }
    };

    // ---- conversions --------------------------------------------------
    conv_bf16<<<2048, blk, 0, stream>>>(vfs, vfs_bf, 1024ll * 12288, 1);
    conv_bf16<<<1024, blk, 0, stream>>>(W_h1, Wh1b, 2048ll * 4096, 0);
    conv_bf16<<<2048, blk, 0, stream>>>(W_h2, Wh2b, 4096ll * 12288, 0);
    conv_bf16<<<512,  blk, 0, stream>>>(W_e1, We1b, 600ll * 2048, 0);
    conv_bf16<<<512,  blk, 0, stream>>>(W_e2, We2b, 600ll * 4096, 0);
    conv_pad<<<1024, blk, 0, stream>>>(W_h, Whb, 1800, 1800, 1856);
    conv_pad<<<512,  blk, 0, stream>>>(W_e, Web, 600, 1800, 1856);
    zero_cols<<<256, blk, 0, stream>>>(z,  1024, 1800, 1856);
    zero_cols<<<256, blk, 0, stream>>>(h2, 1024, 1800, 1856);

    // ---- big GEMMs (256^2 2-phase pipelined split-K) -------------------
    // 1) layer-1 hidden, sbj+obj fused: M=2048, N=2048, K=4096, S=4 -> 256 blk
    gemmBig(vfs_bf, 12288, 8192ll - 1024ll * 12288, 1024,
            Wh1b, 4096, 2048, b_h1, h1, 2048, HUGE_SPLIT, 0,
            2048, 2048, 4096, 4);
    // 2) layer-1 hidden, pre: M=1024, N=4096, K=12288, S=4 -> 256 blk
    gemmBig(vfs_bf, 12288, 0, HUGE_SPLIT,
            Wh2b, 12288, 4096, b_h2, hp, 4096, HUGE_SPLIT, 0,
            1024, 4096, 12288, 4);

    // ---- tail GEMMs (64^2 full-K, direct epilogue) — unchanged ---------
    {
        GDesc d3{h1,  We1b, b_e1, z,       0, 1200ll - 1024ll * 1856,
                 2048, 2048, 600, 1856, 600, 2048, 10, 1024};
        GDesc d4{hp,  We2b, b_e2, z + 600, 0, 0,
                 4096, 4096, 600, 1856, 600, 4096, 10, HUGE_SPLIT};
        gemm64_dual<1, 1><<<dim3(480), blk, 0, stream>>>(d3, d4, 320);
    }
    {
        GDesc d5{z, Whb, b_h, h2, 0, 0,
                 1856, 1856, 1800, 1856, 1800, 1856, 29, HUGE_SPLIT};
        gemm64_dual<1, 1><<<dim3(464), blk, 0, stream>>>(d5, d5, 464);
    }
    {
        GDesc d6{h2, Web, b_e, emb, 0, 0,
                 1856, 1856, 600, 600, 600, 1856, 10, HUGE_SPLIT};
        gemm64_dual<0, 0><<<dim3(160), blk, 0, stream>>>(d6, d6, 160);
    }

    // ---- scores -------------------------------------------------------
    score_kernel<<<dim3(1024), blk, 0, stream>>>(emb, labels, pls, nls, (float*)d_out);
}